// Round 14
// baseline (188.224 us; speedup 1.0000x reference)
//
#include <hip/hip_runtime.h>
#include <hip/hip_bf16.h>
#include <math.h>

typedef __attribute__((ext_vector_type(8))) short s16x8;   // 8 bf16
typedef __attribute__((ext_vector_type(4))) float f32x4;

__device__ __forceinline__ float silu(float a) {
    return a / (1.f + __expf(-a));
}
__device__ __forceinline__ unsigned short f2b(float f) {
    __hip_bfloat16 h = __float2bfloat16(f);
    return *reinterpret_cast<unsigned short*>(&h);
}

// ---------------------------------------------------------------------------
// Kernel 0: weight prep. bf16 B-layout weights + howT for the epilogue.
// ---------------------------------------------------------------------------
__global__ __launch_bounds__(256) void wprep(
    const float* __restrict__ qw1, const float* __restrict__ kw1,
    const float* __restrict__ vw1, const float* __restrict__ qw2,
    const float* __restrict__ kw2, const float* __restrict__ vw2,
    const float* __restrict__ xmw1, const float* __restrict__ xmw2,
    const float* __restrict__ how,
    unsigned short* __restrict__ w1T, unsigned short* __restrict__ w2T,
    unsigned short* __restrict__ xm1T, unsigned short* __restrict__ xm2T,
    unsigned short* __restrict__ howT)
{
    int idx = blockIdx.x * 256 + threadIdx.x;
    if (idx < 98304) {                       // w1T: 3 * 128 * 256
        int m = idx >> 15, r = idx & 32767;
        int n = r >> 8, k = r & 255;
        const float* src = (m == 0) ? qw1 : (m == 1) ? kw1 : vw1;
        w1T[idx] = f2b(src[k * 128 + n]);
    } else if (idx < 147456) {               // w2T: 3 * 128 * 128
        int r0 = idx - 98304;
        int m = r0 >> 14, r = r0 & 16383;
        int n = r >> 7, k = r & 127;
        const float* src = (m == 0) ? qw2 : (m == 1) ? kw2 : vw2;
        w2T[r0] = f2b(src[k * 128 + n]);
    } else if (idx < 163840) {               // xm1T: 128 * 128
        int r = idx - 147456;
        int n = r >> 7, k = r & 127;
        xm1T[r] = f2b(xmw1[k * 128 + n]);
    } else if (idx < 165888) {               // xm2T: 16 * 128
        int r = idx - 163840;
        int n = r >> 7, k = r & 127;
        xm2T[r] = (n < 8) ? f2b(xmw2[k * 8 + n]) : (unsigned short)0;
    } else if (idx < 198656) {               // howT: 256 * 128
        int r = idx - 165888;
        int n = r >> 7, k = r & 127;
        howT[r] = f2b(how[k * 256 + n]);
    }
}

// ---------------------------------------------------------------------------
// Kernel 1: MFMA qkv, ROLE-SPLIT. Grid 1536: blocks 0-511 Q, 512-1023 K,
// 1024-1535 V+xm. 16 tokens/block, 4 waves. Q/K blocks: 2 barriers.
// ---------------------------------------------------------------------------
__global__ __launch_bounds__(256) void qkv_mfma(
    const float* __restrict__ x, const float* __restrict__ h,
    const float* __restrict__ qb1, const float* __restrict__ qb2,
    const float* __restrict__ kb1, const float* __restrict__ kb2,
    const float* __restrict__ vb1, const float* __restrict__ vb2,
    const float* __restrict__ xmb1, const float* __restrict__ xmb2,
    const unsigned short* __restrict__ w1T, const unsigned short* __restrict__ w2T,
    const unsigned short* __restrict__ xm1T, const unsigned short* __restrict__ xm2T,
    unsigned short* __restrict__ q_bf, unsigned short* __restrict__ k_bf,
    unsigned short* __restrict__ vT_bf)
{
    const int blk  = blockIdx.x;
    const int role = blk >> 9;               // 0=q, 1=k, 2=v+xm
    const int tb   = blk & 511;
    const int b    = tb >> 7;
    const int t0   = (tb & 127) << 4;
    const int tid  = threadIdx.x;
    const int nq   = tid >> 6;
    const int lane = tid & 63;
    const int m_   = lane & 15;
    const int quad = lane >> 4;

    __shared__ __align__(16) unsigned short hA[16][264];
    __shared__ __align__(16) unsigned short hidA[16][136];
    __shared__ __align__(16) unsigned short voutA[16][136];
    __shared__ float vxs[16][8];

    #pragma unroll
    for (int g = 0; g < 4; g++) {
        float4 hv = *(const float4*)(h + ((size_t)(b * 256 + tid)) * 2048
                                       + t0 + g * 4);
        hA[g * 4 + 0][tid] = f2b(hv.x);
        hA[g * 4 + 1][tid] = f2b(hv.y);
        hA[g * 4 + 2][tid] = f2b(hv.z);
        hA[g * 4 + 3][tid] = f2b(hv.w);
    }
    __syncthreads();                         // B1

    const f32x4 zero = {0.f, 0.f, 0.f, 0.f};
    const float* b1 = (role == 0) ? qb1 : (role == 1) ? kb1 : vb1;
    const float* b2 = (role == 0) ? qb2 : (role == 1) ? kb2 : vb2;
    const unsigned short* w1m = w1T + role * 32768;
    const unsigned short* w2m = w2T + role * 16384;

    // ---- gemm1 (K=256) -> silu -> hidA ----
    {
        f32x4 acc[2] = {zero, zero};
        #pragma unroll
        for (int kc = 0; kc < 8; kc++) {
            s16x8 af = *(const s16x8*)&hA[m_][kc * 32 + quad * 8];
            #pragma unroll
            for (int nt = 0; nt < 2; nt++) {
                const s16x8 bf = *(const s16x8*)(w1m
                    + (size_t)(nq * 32 + nt * 16 + m_) * 256 + kc * 32 + quad * 8);
                acc[nt] = __builtin_amdgcn_mfma_f32_16x16x32_bf16(
                    af, bf, acc[nt], 0, 0, 0);
            }
        }
        #pragma unroll
        for (int nt = 0; nt < 2; nt++) {
            int col = nq * 32 + nt * 16 + m_;
            float bia = b1[col];
            #pragma unroll
            for (int i = 0; i < 4; i++)
                hidA[quad * 4 + i][col] = f2b(silu(acc[nt][i] + bia));
        }
    }
    __syncthreads();                         // B2

    // ---- gemm2 (K=128) ----
    f32x4 acc[2] = {zero, zero};
    #pragma unroll
    for (int kc = 0; kc < 4; kc++) {
        s16x8 af = *(const s16x8*)&hidA[m_][kc * 32 + quad * 8];
        #pragma unroll
        for (int nt = 0; nt < 2; nt++) {
            const s16x8 bf = *(const s16x8*)(w2m
                + (size_t)(nq * 32 + nt * 16 + m_) * 128 + kc * 32 + quad * 8);
            acc[nt] = __builtin_amdgcn_mfma_f32_16x16x32_bf16(
                af, bf, acc[nt], 0, 0, 0);
        }
    }

    if (role < 2) {
        // RoPE + store q/k
        unsigned short* dst = (role == 0) ? q_bf : k_bf;
        float scale = (role == 0) ? 0.25f : 1.0f;
        #pragma unroll
        for (int nt = 0; nt < 2; nt++) {
            int col  = nq * 32 + nt * 16 + m_;
            int head = col >> 4, dim = col & 15;
            float inv = exp2f(-(float)(dim >> 1) * 0.125f * 13.28771238f);
            float bia = b2[col];
            #pragma unroll
            for (int i = 0; i < 4; i++) {
                int t = t0 + quad * 4 + i;
                float a  = acc[nt][i] + bia;
                float pr = __shfl_xor(a, 1);
                float f  = (float)t * inv;
                float cs = cosf(f), sn = sinf(f);
                float o  = (dim & 1) ? (a * cs + pr * sn) : (a * cs - pr * sn);
                dst[((size_t)(b * 8 + head) * 2048 + t) * 16 + dim] =
                    f2b(o * scale);
            }
        }
        return;
    }

    // ---- role 2: v + xm ----
    #pragma unroll
    for (int nt = 0; nt < 2; nt++) {
        int col = nq * 32 + nt * 16 + m_;
        float bia = b2[col];
        #pragma unroll
        for (int i = 0; i < 4; i++)
            voutA[quad * 4 + i][col] = f2b(acc[nt][i] + bia);
    }
    __syncthreads();                         // B3

    {
        int col = tid >> 1, tg = tid & 1;
        s16x8 pk;
        #pragma unroll
        for (int e = 0; e < 8; e++)
            pk[e] = (short)voutA[tg * 8 + e][col];
        *(s16x8*)(vT_bf + ((size_t)(b * 8 + (col >> 4)) * 32 + (col & 15)) * 2048
                        + t0 + tg * 8) = pk;
    }
    {
        f32x4 a1[2] = {zero, zero};
        #pragma unroll
        for (int kc = 0; kc < 4; kc++) {
            s16x8 af = *(const s16x8*)&voutA[m_][kc * 32 + quad * 8];
            #pragma unroll
            for (int nt = 0; nt < 2; nt++) {
                const s16x8 bf = *(const s16x8*)(xm1T
                    + (size_t)(nq * 32 + nt * 16 + m_) * 128 + kc * 32 + quad * 8);
                a1[nt] = __builtin_amdgcn_mfma_f32_16x16x32_bf16(
                    af, bf, a1[nt], 0, 0, 0);
            }
        }
        __syncthreads();                     // B4 (hidA WAR)
        #pragma unroll
        for (int nt = 0; nt < 2; nt++) {
            int col = nq * 32 + nt * 16 + m_;
            float bia = xmb1[col];
            #pragma unroll
            for (int i = 0; i < 4; i++)
                hidA[quad * 4 + i][col] = f2b(silu(a1[nt][i] + bia));
        }
    }
    __syncthreads();                         // B5

    if (nq == 0) {
        f32x4 a2 = zero;
        #pragma unroll
        for (int kc = 0; kc < 4; kc++) {
            s16x8 af = *(const s16x8*)&hidA[m_][kc * 32 + quad * 8];
            const s16x8 bf = *(const s16x8*)(xm2T
                + (size_t)m_ * 128 + kc * 32 + quad * 8);
            a2 = __builtin_amdgcn_mfma_f32_16x16x32_bf16(af, bf, a2, 0, 0, 0);
        }
        if (m_ < 8) {
            float bia = xmb2[m_];
            #pragma unroll
            for (int i = 0; i < 4; i++)
                vxs[quad * 4 + i][m_] = a2[i] + bia;
        }
    }
    __syncthreads();                         // B6

    #pragma unroll
    for (int r = 0; r < 2; r++) {
        int i  = tid + r * 256;
        int hh = i >> 6, c = (i >> 4) & 3, tt = i & 15;
        float val = vxs[tt][hh];
        if (c)
            val *= x[((size_t)(b * 3 + (c - 1))) * 2048 + t0 + tt];
        vT_bf[((size_t)(b * 8 + hh) * 32 + 16 + c) * 2048 + t0 + tt] = f2b(val);
    }
    if (tid < 192) {
        int hh = tid / 24, rem = tid % 24;
        int c  = 20 + (rem >> 1), tg = rem & 1;
        s16x8 z = {0,0,0,0,0,0,0,0};
        *(s16x8*)(vT_bf + ((size_t)(b * 8 + hh) * 32 + c) * 2048
                        + t0 + tg * 8) = z;
    }
}

// ---------------------------------------------------------------------------
// Kernel 2: MFMA attention, 4-WAY key split, 64 queries per wave.
// Single-wave blocks: grid 4*32*32 = 4096 (16 blocks/CU), 8 tiles per wave.
// Emits UNNORMALIZED O (cols 0..19) and l (col 20) into opart[sp][bh][t][24].
// ---------------------------------------------------------------------------
__global__ __launch_bounds__(64) void attn_mfma(
    const unsigned short* __restrict__ q_bf,
    const unsigned short* __restrict__ k_bf,
    const unsigned short* __restrict__ vT_bf,
    float* __restrict__ opart)
{
    const int blk  = blockIdx.x;
    const int sp   = blk >> 10;              // key split 0..3
    const int bh   = (blk >> 5) & 31;
    const int qs   = (blk & 31) << 6;        // 64-query strip
    const int lane = threadIdx.x;
    const int m_   = lane & 15;
    const int quad = lane >> 4;

    __shared__ __align__(16) unsigned short Elds[4][2][16 * 72];

    const s16x8 zs = {0, 0, 0, 0, 0, 0, 0, 0};
    const f32x4 zero = {0.f, 0.f, 0.f, 0.f};

    s16x8 qfrag[4];
    #pragma unroll
    for (int qt = 0; qt < 4; qt++) {
        qfrag[qt] = zs;
        if (quad < 2)
            qfrag[qt] = *(const s16x8*)(q_bf +
                ((size_t)(bh * 2048 + qs + qt * 16 + m_) * 16 + quad * 8));
    }

    f32x4 O0[4], O1[4];
    float lsq[4];
    #pragma unroll
    for (int qt = 0; qt < 4; qt++) {
        O0[qt] = zero; O1[qt] = zero; lsq[qt] = 0.f;
    }

    const unsigned short* kb = k_bf + ((size_t)bh * 2048 + sp * 512) * 16;
    const unsigned short* vb = vT_bf + (size_t)bh * 32 * 2048 + sp * 512;

    for (int kt = 0; kt < 8; kt++) {         // 8 tiles of 64 keys
        const int k0 = kt * 64;
        const int buf = kt & 1;

        s16x8 kf[4];
        #pragma unroll
        for (int n = 0; n < 4; n++) {
            kf[n] = zs;
            if (quad < 2)
                kf[n] = *(const s16x8*)(kb +
                      ((size_t)(k0 + n * 16 + m_) * 16 + quad * 8));
        }
        s16x8 vf0[2], vf1[2];
        #pragma unroll
        for (int c = 0; c < 2; c++) {
            vf0[c] = *(const s16x8*)(vb + (size_t)m_ * 2048
                                        + k0 + c * 32 + quad * 8);
            vf1[c] = *(const s16x8*)(vb + (size_t)(16 + m_) * 2048
                                        + k0 + c * 32 + quad * 8);
        }

        #pragma unroll
        for (int qt = 0; qt < 4; qt++) {
            #pragma unroll
            for (int n = 0; n < 4; n++) {
                f32x4 E = __builtin_amdgcn_mfma_f32_16x16x32_bf16(
                    kf[n], qfrag[qt], zero, 0, 0, 0);
                float e0 = __expf(E[0]);
                float e1 = __expf(E[1]);
                float e2 = __expf(E[2]);
                float e3 = __expf(E[3]);
                lsq[qt] += e0 + e1 + e2 + e3;
                uint2 pk;
                pk.x = (unsigned)f2b(e0) | ((unsigned)f2b(e1) << 16);
                pk.y = (unsigned)f2b(e2) | ((unsigned)f2b(e3) << 16);
                *(uint2*)&Elds[qt][buf][m_ * 72 + n * 16 + quad * 4] = pk;
            }
        }
        __builtin_amdgcn_s_waitcnt(0xc07f);  // lgkmcnt(0), wave-local

        #pragma unroll
        for (int qt = 0; qt < 4; qt++) {
            #pragma unroll
            for (int c = 0; c < 2; c++) {
                s16x8 af = *(const s16x8*)
                    &Elds[qt][buf][m_ * 72 + c * 32 + quad * 8];
                O0[qt] = __builtin_amdgcn_mfma_f32_16x16x32_bf16(
                    af, vf0[c], O0[qt], 0, 0, 0);
                O1[qt] = __builtin_amdgcn_mfma_f32_16x16x32_bf16(
                    af, vf1[c], O1[qt], 0, 0, 0);
            }
        }
    }

    #pragma unroll
    for (int qt = 0; qt < 4; qt++) {
        float s = lsq[qt];
        s += __shfl_xor(s, 16);
        s += __shfl_xor(s, 32);
        float* opb = opart + ((size_t)(sp * 32 + bh) * 2048 + qs + qt * 16) * 24;
        #pragma unroll
        for (int i = 0; i < 4; i++) {
            int row = quad * 4 + i;
            float* ob = opb + row * 24;
            ob[m_] = O0[qt][i];
            if (m_ < 4) ob[16 + m_] = O1[qt][i];
        }
        if (quad == 0) opb[m_ * 24 + 20] = s;
    }
}

// ---------------------------------------------------------------------------
// Kernel 3: MFMA epilogue, 4-split combine. 16 tokens/block, grid 512.
// ---------------------------------------------------------------------------
__global__ __launch_bounds__(256) void epi_kernel(
    const float* __restrict__ opart, const unsigned short* __restrict__ howT,
    const float* __restrict__ x, const float* __restrict__ hin,
    const float* __restrict__ hob,
    const float* __restrict__ Wh, const float* __restrict__ Wu,
    float* __restrict__ out)
{
    const int blk = blockIdx.x;
    const int b  = blk >> 7;
    const int t0 = (blk & 127) << 4;
    const int tid = threadIdx.x;
    const int nq   = tid >> 6;
    const int lane = tid & 63;
    const int m_   = lane & 15;
    const int quad = lane >> 4;
    const size_t qtr = (size_t)32 * 2048 * 24;

    __shared__ __align__(16) unsigned short hvA[16][136];
    __shared__ float linv[8][16];
    __shared__ float gamma[8][16], wx[8][3][16];
    __shared__ float weff[8];

    auto comb = [&](size_t off) -> float {
        return opart[off] + opart[qtr + off] + opart[2 * qtr + off]
             + opart[3 * qtr + off];
    };

    if (tid < 128) {
        int hh = tid >> 4, tt = tid & 15;
        size_t off = ((size_t)(b * 8 + hh) * 2048 + t0 + tt) * 24 + 20;
        linv[hh][tt] = 1.f / comb(off);
    } else if (tid < 136) {
        int v = tid - 128;
        float s = 0.f;
        for (int j = 0; j < 8; j++) s += Wh[v * 8 + j] * Wu[j];
        weff[v] = s;
    }
    __syncthreads();

    #pragma unroll
    for (int r = 0; r < 8; r++) {
        int i = tid + r * 256;
        int jj = i >> 4, tt = i & 15;
        size_t off = ((size_t)(b * 8 + (jj >> 4)) * 2048 + t0 + tt) * 24
                   + (jj & 15);
        hvA[tt][jj] = f2b(comb(off) * linv[jj >> 4][tt]);
    }
    #pragma unroll
    for (int r = 0; r < 2; r++) {
        int i = tid + r * 256;
        int hh = i >> 6, c = (i >> 4) & 3, tt = i & 15;
        size_t off = ((size_t)(b * 8 + hh) * 2048 + t0 + tt) * 24 + 16 + c;
        float v = comb(off) * linv[hh][tt];
        if (c == 0) gamma[hh][tt] = v; else wx[hh][c - 1][tt] = v;
    }
    __syncthreads();

    const f32x4 zero = {0.f, 0.f, 0.f, 0.f};
    #pragma unroll
    for (int nt = 0; nt < 4; nt++) {
        int col = nq * 64 + nt * 16 + m_;
        f32x4 acc = zero;
        #pragma unroll
        for (int kc = 0; kc < 4; kc++) {
            s16x8 af = *(const s16x8*)&hvA[m_][kc * 32 + quad * 8];
            const s16x8 bf = *(const s16x8*)(howT
                + (size_t)col * 128 + kc * 32 + quad * 8);
            acc = __builtin_amdgcn_mfma_f32_16x16x32_bf16(af, bf, acc, 0, 0, 0);
        }
        float bia = hob[col];
        size_t base = ((size_t)b * 256 + col) * 2048 + t0 + quad * 4;
        float4 hold = *(const float4*)(hin + base);
        float4 hres;
        hres.x = hold.x + acc[0] + bia;
        hres.y = hold.y + acc[1] + bia;
        hres.z = hold.z + acc[2] + bia;
        hres.w = hold.w + acc[3] + bia;
        *(float4*)(out + 24576 + base) = hres;
    }

    if (tid < 16) {
        int tt = tid;
        int t = t0 + tt;
        float Vu[3], xv[3];
        #pragma unroll
        for (int c = 0; c < 3; c++) {
            xv[c] = x[((size_t)b * 3 + c) * 2048 + t];
            float s = 0.f;
            #pragma unroll
            for (int v = 0; v < 8; v++)
                s += (gamma[v][tt] * xv[c] - wx[v][c][tt]) * weff[v];
            Vu[c] = s;
        }
        float gate = sqrtf(Vu[0]*Vu[0] + Vu[1]*Vu[1] + Vu[2]*Vu[2]);
        float sg = 1.f / (1.f + __expf(-gate));
        #pragma unroll
        for (int c = 0; c < 3; c++)
            out[((size_t)b * 3 + c) * 2048 + t] = xv[c] + sg * Vu[c];
    }
}

// ---------------------------------------------------------------------------
extern "C" void kernel_launch(void* const* d_in, const int* in_sizes, int n_in,
                              void* d_out, int out_size, void* d_ws,
                              size_t ws_size, hipStream_t stream)
{
    const float* x    = (const float*)d_in[0];
    const float* h    = (const float*)d_in[1];
    const float* qw1  = (const float*)d_in[2];
    const float* qb1  = (const float*)d_in[3];
    const float* qw2  = (const float*)d_in[4];
    const float* qb2  = (const float*)d_in[5];
    const float* kw1  = (const float*)d_in[6];
    const float* kb1  = (const float*)d_in[7];
    const float* kw2  = (const float*)d_in[8];
    const float* kb2  = (const float*)d_in[9];
    const float* vw1  = (const float*)d_in[10];
    const float* vb1  = (const float*)d_in[11];
    const float* vw2  = (const float*)d_in[12];
    const float* vb2  = (const float*)d_in[13];
    const float* xmw1 = (const float*)d_in[14];
    const float* xmb1 = (const float*)d_in[15];
    const float* xmw2 = (const float*)d_in[16];
    const float* xmb2 = (const float*)d_in[17];
    const float* how  = (const float*)d_in[18];
    const float* hob  = (const float*)d_in[19];
    const float* Wh   = (const float*)d_in[20];
    const float* Wu   = (const float*)d_in[21];
    float* out = (float*)d_out;

    unsigned short* q_bf  = (unsigned short*)d_ws;          // 32*2048*16 us
    unsigned short* k_bf  = q_bf + (size_t)32 * 2048 * 16;
    unsigned short* vT_bf = k_bf + (size_t)32 * 2048 * 16;  // 32*32*2048 us
    float* opart = (float*)(vT_bf + (size_t)32 * 32 * 2048); // 4*32*2048*24 f
    unsigned short* w1T  = (unsigned short*)(opart + (size_t)4 * 32 * 2048 * 24);
    unsigned short* w2T  = w1T + 98304;
    unsigned short* xm1T = w2T + 49152;
    unsigned short* xm2T = xm1T + 16384;
    unsigned short* howT = xm2T + 2048;                     // 32768 us

    wprep<<<776, 256, 0, stream>>>(qw1, kw1, vw1, qw2, kw2, vw2, xmw1, xmw2,
                                   how, w1T, w2T, xm1T, xm2T, howT);
    qkv_mfma<<<1536, 256, 0, stream>>>(
        x, h, qb1, qb2, kb1, kb2, vb1, vb2, xmb1, xmb2,
        w1T, w2T, xm1T, xm2T, q_bf, k_bf, vT_bf);
    attn_mfma<<<4096, 64, 0, stream>>>(q_bf, k_bf, vT_bf, opart);
    epi_kernel<<<512, 256, 0, stream>>>(opart, howT, x, h, hob, Wh, Wu, out);
}

// Round 15
// 186.387 us; speedup vs baseline: 1.0099x; 1.0099x over previous
//
#include <hip/hip_runtime.h>
#include <hip/hip_bf16.h>
#include <math.h>

typedef __attribute__((ext_vector_type(8))) short s16x8;   // 8 bf16
typedef __attribute__((ext_vector_type(4))) float f32x4;

__device__ __forceinline__ float silu(float a) {
    return a / (1.f + __expf(-a));
}
__device__ __forceinline__ unsigned short f2b(float f) {
    __hip_bfloat16 h = __float2bfloat16(f);
    return *reinterpret_cast<unsigned short*>(&h);
}

// ---------------------------------------------------------------------------
// Kernel 0: weight prep. bf16 B-layout weights + howT for the epilogue.
// ---------------------------------------------------------------------------
__global__ __launch_bounds__(256) void wprep(
    const float* __restrict__ qw1, const float* __restrict__ kw1,
    const float* __restrict__ vw1, const float* __restrict__ qw2,
    const float* __restrict__ kw2, const float* __restrict__ vw2,
    const float* __restrict__ xmw1, const float* __restrict__ xmw2,
    const float* __restrict__ how,
    unsigned short* __restrict__ w1T, unsigned short* __restrict__ w2T,
    unsigned short* __restrict__ xm1T, unsigned short* __restrict__ xm2T,
    unsigned short* __restrict__ howT)
{
    int idx = blockIdx.x * 256 + threadIdx.x;
    if (idx < 98304) {                       // w1T: 3 * 128 * 256
        int m = idx >> 15, r = idx & 32767;
        int n = r >> 8, k = r & 255;
        const float* src = (m == 0) ? qw1 : (m == 1) ? kw1 : vw1;
        w1T[idx] = f2b(src[k * 128 + n]);
    } else if (idx < 147456) {               // w2T: 3 * 128 * 128
        int r0 = idx - 98304;
        int m = r0 >> 14, r = r0 & 16383;
        int n = r >> 7, k = r & 127;
        const float* src = (m == 0) ? qw2 : (m == 1) ? kw2 : vw2;
        w2T[r0] = f2b(src[k * 128 + n]);
    } else if (idx < 163840) {               // xm1T: 128 * 128
        int r = idx - 147456;
        int n = r >> 7, k = r & 127;
        xm1T[r] = f2b(xmw1[k * 128 + n]);
    } else if (idx < 165888) {               // xm2T: 16 * 128
        int r = idx - 163840;
        int n = r >> 7, k = r & 127;
        xm2T[r] = (n < 8) ? f2b(xmw2[k * 8 + n]) : (unsigned short)0;
    } else if (idx < 198656) {               // howT: 256 * 128
        int r = idx - 165888;
        int n = r >> 7, k = r & 127;
        howT[r] = f2b(how[k * 256 + n]);
    }
}

// ---------------------------------------------------------------------------
// Kernel 1: MFMA qkv (r13 batched version — best measured). 16 tokens/block,
// 4 waves, grid 512. Batched gemm1 (q,k,v share hA -> 48 MFMAs), one barrier,
// batched gemm2 + RoPE stores. 5 barriers total.
// ---------------------------------------------------------------------------
__global__ __launch_bounds__(256) void qkv_mfma(
    const float* __restrict__ x, const float* __restrict__ h,
    const float* __restrict__ qb1, const float* __restrict__ qb2,
    const float* __restrict__ kb1, const float* __restrict__ kb2,
    const float* __restrict__ vb1, const float* __restrict__ vb2,
    const float* __restrict__ xmb1, const float* __restrict__ xmb2,
    const unsigned short* __restrict__ w1T, const unsigned short* __restrict__ w2T,
    const unsigned short* __restrict__ xm1T, const unsigned short* __restrict__ xm2T,
    unsigned short* __restrict__ q_bf, unsigned short* __restrict__ k_bf,
    unsigned short* __restrict__ vT_bf)
{
    const int blk = blockIdx.x;
    const int b   = blk >> 7;
    const int t0  = (blk & 127) << 4;
    const int tid = threadIdx.x;
    const int nq   = tid >> 6;
    const int lane = tid & 63;
    const int m_   = lane & 15;
    const int quad = lane >> 4;

    __shared__ __align__(16) unsigned short hA[16][264];
    __shared__ __align__(16) unsigned short hidQ[16][136];
    __shared__ __align__(16) unsigned short hidK[16][136];
    __shared__ __align__(16) unsigned short hidV[16][136];
    __shared__ __align__(16) unsigned short voutA[16][136];
    __shared__ float vxs[16][8];

    #pragma unroll
    for (int g = 0; g < 4; g++) {
        float4 hv = *(const float4*)(h + ((size_t)(b * 256 + tid)) * 2048
                                       + t0 + g * 4);
        hA[g * 4 + 0][tid] = f2b(hv.x);
        hA[g * 4 + 1][tid] = f2b(hv.y);
        hA[g * 4 + 2][tid] = f2b(hv.z);
        hA[g * 4 + 3][tid] = f2b(hv.w);
    }
    __syncthreads();                         // B1

    const f32x4 zero = {0.f, 0.f, 0.f, 0.f};

    {
        f32x4 aQ[2] = {zero, zero}, aK[2] = {zero, zero}, aV[2] = {zero, zero};
        #pragma unroll
        for (int kc = 0; kc < 8; kc++) {
            s16x8 af = *(const s16x8*)&hA[m_][kc * 32 + quad * 8];
            #pragma unroll
            for (int nt = 0; nt < 2; nt++) {
                size_t woff = (size_t)(nq * 32 + nt * 16 + m_) * 256
                            + kc * 32 + quad * 8;
                aQ[nt] = __builtin_amdgcn_mfma_f32_16x16x32_bf16(
                    af, *(const s16x8*)(w1T + woff), aQ[nt], 0, 0, 0);
                aK[nt] = __builtin_amdgcn_mfma_f32_16x16x32_bf16(
                    af, *(const s16x8*)(w1T + 32768 + woff), aK[nt], 0, 0, 0);
                aV[nt] = __builtin_amdgcn_mfma_f32_16x16x32_bf16(
                    af, *(const s16x8*)(w1T + 65536 + woff), aV[nt], 0, 0, 0);
            }
        }
        #pragma unroll
        for (int nt = 0; nt < 2; nt++) {
            int col = nq * 32 + nt * 16 + m_;
            float bq = qb1[col], bk = kb1[col], bv = vb1[col];
            #pragma unroll
            for (int i = 0; i < 4; i++) {
                hidQ[quad * 4 + i][col] = f2b(silu(aQ[nt][i] + bq));
                hidK[quad * 4 + i][col] = f2b(silu(aK[nt][i] + bk));
                hidV[quad * 4 + i][col] = f2b(silu(aV[nt][i] + bv));
            }
        }
    }
    __syncthreads();                         // B2

    auto gemm2 = [&](const unsigned short* w2m,
                     unsigned short (*hid)[136], f32x4 acc[2]) {
        #pragma unroll
        for (int kc = 0; kc < 4; kc++) {
            s16x8 af = *(const s16x8*)&hid[m_][kc * 32 + quad * 8];
            #pragma unroll
            for (int nt = 0; nt < 2; nt++) {
                const s16x8 bf = *(const s16x8*)(w2m
                    + (size_t)(nq * 32 + nt * 16 + m_) * 128 + kc * 32 + quad * 8);
                acc[nt] = __builtin_amdgcn_mfma_f32_16x16x32_bf16(
                    af, bf, acc[nt], 0, 0, 0);
            }
        }
    };
    auto rope_store = [&](f32x4 acc[2], const float* b2,
                          unsigned short* dst, float scale) {
        #pragma unroll
        for (int nt = 0; nt < 2; nt++) {
            int col  = nq * 32 + nt * 16 + m_;
            int head = col >> 4, dim = col & 15;
            float inv = exp2f(-(float)(dim >> 1) * 0.125f * 13.28771238f);
            float bia = b2[col];
            #pragma unroll
            for (int i = 0; i < 4; i++) {
                int t = t0 + quad * 4 + i;
                float a  = acc[nt][i] + bia;
                float pr = __shfl_xor(a, 1);
                float f  = (float)t * inv;
                float cs = cosf(f), sn = sinf(f);
                float o  = (dim & 1) ? (a * cs + pr * sn) : (a * cs - pr * sn);
                dst[((size_t)(b * 8 + head) * 2048 + t) * 16 + dim] =
                    f2b(o * scale);
            }
        }
    };

    {
        f32x4 aQ[2] = {zero, zero}, aK[2] = {zero, zero}, aV[2] = {zero, zero};
        gemm2(w2T,         hidQ, aQ);
        gemm2(w2T + 16384, hidK, aK);
        gemm2(w2T + 32768, hidV, aV);
        rope_store(aQ, qb2, q_bf, 0.25f);
        rope_store(aK, kb2, k_bf, 1.0f);
        #pragma unroll
        for (int nt = 0; nt < 2; nt++) {
            int col = nq * 32 + nt * 16 + m_;
            float bia = vb2[col];
            #pragma unroll
            for (int i = 0; i < 4; i++)
                voutA[quad * 4 + i][col] = f2b(aV[nt][i] + bia);
        }
    }
    __syncthreads();                         // B3

    {
        int col = tid >> 1, tg = tid & 1;
        s16x8 pk;
        #pragma unroll
        for (int e = 0; e < 8; e++)
            pk[e] = (short)voutA[tg * 8 + e][col];
        *(s16x8*)(vT_bf + ((size_t)(b * 8 + (col >> 4)) * 32 + (col & 15)) * 2048
                        + t0 + tg * 8) = pk;
    }
    {
        f32x4 acc[2] = {zero, zero};
        #pragma unroll
        for (int kc = 0; kc < 4; kc++) {
            s16x8 af = *(const s16x8*)&voutA[m_][kc * 32 + quad * 8];
            #pragma unroll
            for (int nt = 0; nt < 2; nt++) {
                const s16x8 bf = *(const s16x8*)(xm1T
                    + (size_t)(nq * 32 + nt * 16 + m_) * 128 + kc * 32 + quad * 8);
                acc[nt] = __builtin_amdgcn_mfma_f32_16x16x32_bf16(
                    af, bf, acc[nt], 0, 0, 0);
            }
        }
        #pragma unroll
        for (int nt = 0; nt < 2; nt++) {
            int col = nq * 32 + nt * 16 + m_;
            float bia = xmb1[col];
            #pragma unroll
            for (int i = 0; i < 4; i++)
                hidQ[quad * 4 + i][col] = f2b(silu(acc[nt][i] + bia));
        }
    }
    __syncthreads();                         // B4

    if (nq == 0) {
        f32x4 a2 = zero;
        #pragma unroll
        for (int kc = 0; kc < 4; kc++) {
            s16x8 af = *(const s16x8*)&hidQ[m_][kc * 32 + quad * 8];
            const s16x8 bf = *(const s16x8*)(xm2T
                + (size_t)m_ * 128 + kc * 32 + quad * 8);
            a2 = __builtin_amdgcn_mfma_f32_16x16x32_bf16(af, bf, a2, 0, 0, 0);
        }
        if (m_ < 8) {
            float bia = xmb2[m_];
            #pragma unroll
            for (int i = 0; i < 4; i++)
                vxs[quad * 4 + i][m_] = a2[i] + bia;
        }
    }
    __syncthreads();                         // B5

    #pragma unroll
    for (int r = 0; r < 2; r++) {
        int i  = tid + r * 256;
        int hh = i >> 6, c = (i >> 4) & 3, tt = i & 15;
        float val = vxs[tt][hh];
        if (c)
            val *= x[((size_t)(b * 3 + (c - 1))) * 2048 + t0 + tt];
        vT_bf[((size_t)(b * 8 + hh) * 32 + 16 + c) * 2048 + t0 + tt] = f2b(val);
    }
    if (tid < 192) {
        int hh = tid / 24, rem = tid % 24;
        int c  = 20 + (rem >> 1), tg = rem & 1;
        s16x8 z = {0,0,0,0,0,0,0,0};
        *(s16x8*)(vT_bf + ((size_t)(b * 8 + hh) * 32 + c) * 2048
                        + t0 + tg * 8) = z;
    }
}

// ---------------------------------------------------------------------------
// Kernel 2: MFMA attention, 4-way key split, 64 queries/wave, SINGLE-BUFFER
// Elds (9.2 KB/block -> 16 blocks/CU; same-wave DS ordering makes WAR safe,
// lgkmcnt(0) covers RAW). Grid 4096 single-wave blocks.
// ---------------------------------------------------------------------------
__global__ __launch_bounds__(64) void attn_mfma(
    const unsigned short* __restrict__ q_bf,
    const unsigned short* __restrict__ k_bf,
    const unsigned short* __restrict__ vT_bf,
    float* __restrict__ opart)
{
    const int blk  = blockIdx.x;
    const int sp   = blk >> 10;              // key split 0..3
    const int bh   = (blk >> 5) & 31;
    const int qs   = (blk & 31) << 6;        // 64-query strip
    const int lane = threadIdx.x;
    const int m_   = lane & 15;
    const int quad = lane >> 4;

    __shared__ __align__(16) unsigned short Elds[4][16 * 72];

    const s16x8 zs = {0, 0, 0, 0, 0, 0, 0, 0};
    const f32x4 zero = {0.f, 0.f, 0.f, 0.f};

    s16x8 qfrag[4];
    #pragma unroll
    for (int qt = 0; qt < 4; qt++) {
        qfrag[qt] = zs;
        if (quad < 2)
            qfrag[qt] = *(const s16x8*)(q_bf +
                ((size_t)(bh * 2048 + qs + qt * 16 + m_) * 16 + quad * 8));
    }

    f32x4 O0[4], O1[4];
    float lsq[4];
    #pragma unroll
    for (int qt = 0; qt < 4; qt++) {
        O0[qt] = zero; O1[qt] = zero; lsq[qt] = 0.f;
    }

    const unsigned short* kb = k_bf + ((size_t)bh * 2048 + sp * 512) * 16;
    const unsigned short* vb = vT_bf + (size_t)bh * 32 * 2048 + sp * 512;

    for (int kt = 0; kt < 8; kt++) {         // 8 tiles of 64 keys
        const int k0 = kt * 64;

        s16x8 kf[4];
        #pragma unroll
        for (int n = 0; n < 4; n++) {
            kf[n] = zs;
            if (quad < 2)
                kf[n] = *(const s16x8*)(kb +
                      ((size_t)(k0 + n * 16 + m_) * 16 + quad * 8));
        }
        s16x8 vf0[2], vf1[2];
        #pragma unroll
        for (int c = 0; c < 2; c++) {
            vf0[c] = *(const s16x8*)(vb + (size_t)m_ * 2048
                                        + k0 + c * 32 + quad * 8);
            vf1[c] = *(const s16x8*)(vb + (size_t)(16 + m_) * 2048
                                        + k0 + c * 32 + quad * 8);
        }

        #pragma unroll
        for (int qt = 0; qt < 4; qt++) {
            #pragma unroll
            for (int n = 0; n < 4; n++) {
                f32x4 E = __builtin_amdgcn_mfma_f32_16x16x32_bf16(
                    kf[n], qfrag[qt], zero, 0, 0, 0);
                float e0 = __expf(E[0]);
                float e1 = __expf(E[1]);
                float e2 = __expf(E[2]);
                float e3 = __expf(E[3]);
                lsq[qt] += e0 + e1 + e2 + e3;
                uint2 pk;
                pk.x = (unsigned)f2b(e0) | ((unsigned)f2b(e1) << 16);
                pk.y = (unsigned)f2b(e2) | ((unsigned)f2b(e3) << 16);
                *(uint2*)&Elds[qt][m_ * 72 + n * 16 + quad * 4] = pk;
            }
        }
        __builtin_amdgcn_s_waitcnt(0xc07f);  // lgkmcnt(0), wave-local RAW

        #pragma unroll
        for (int qt = 0; qt < 4; qt++) {
            #pragma unroll
            for (int c = 0; c < 2; c++) {
                s16x8 af = *(const s16x8*)
                    &Elds[qt][m_ * 72 + c * 32 + quad * 8];
                O0[qt] = __builtin_amdgcn_mfma_f32_16x16x32_bf16(
                    af, vf0[c], O0[qt], 0, 0, 0);
                O1[qt] = __builtin_amdgcn_mfma_f32_16x16x32_bf16(
                    af, vf1[c], O1[qt], 0, 0, 0);
            }
        }
    }

    #pragma unroll
    for (int qt = 0; qt < 4; qt++) {
        float s = lsq[qt];
        s += __shfl_xor(s, 16);
        s += __shfl_xor(s, 32);
        float* opb = opart + ((size_t)(sp * 32 + bh) * 2048 + qs + qt * 16) * 24;
        #pragma unroll
        for (int i = 0; i < 4; i++) {
            int row = quad * 4 + i;
            float* ob = opb + row * 24;
            ob[m_] = O0[qt][i];
            if (m_ < 4) ob[16 + m_] = O1[qt][i];
        }
        if (quad == 0) opb[m_ * 24 + 20] = s;
    }
}

// ---------------------------------------------------------------------------
// Kernel 3: MFMA epilogue, 4-split combine. 16 tokens/block, grid 512.
// ---------------------------------------------------------------------------
__global__ __launch_bounds__(256) void epi_kernel(
    const float* __restrict__ opart, const unsigned short* __restrict__ howT,
    const float* __restrict__ x, const float* __restrict__ hin,
    const float* __restrict__ hob,
    const float* __restrict__ Wh, const float* __restrict__ Wu,
    float* __restrict__ out)
{
    const int blk = blockIdx.x;
    const int b  = blk >> 7;
    const int t0 = (blk & 127) << 4;
    const int tid = threadIdx.x;
    const int nq   = tid >> 6;
    const int lane = tid & 63;
    const int m_   = lane & 15;
    const int quad = lane >> 4;
    const size_t qtr = (size_t)32 * 2048 * 24;

    __shared__ __align__(16) unsigned short hvA[16][136];
    __shared__ float linv[8][16];
    __shared__ float gamma[8][16], wx[8][3][16];
    __shared__ float weff[8];

    auto comb = [&](size_t off) -> float {
        return opart[off] + opart[qtr + off] + opart[2 * qtr + off]
             + opart[3 * qtr + off];
    };

    if (tid < 128) {
        int hh = tid >> 4, tt = tid & 15;
        size_t off = ((size_t)(b * 8 + hh) * 2048 + t0 + tt) * 24 + 20;
        linv[hh][tt] = 1.f / comb(off);
    } else if (tid < 136) {
        int v = tid - 128;
        float s = 0.f;
        for (int j = 0; j < 8; j++) s += Wh[v * 8 + j] * Wu[j];
        weff[v] = s;
    }
    __syncthreads();

    #pragma unroll
    for (int r = 0; r < 8; r++) {
        int i = tid + r * 256;
        int jj = i >> 4, tt = i & 15;
        size_t off = ((size_t)(b * 8 + (jj >> 4)) * 2048 + t0 + tt) * 24
                   + (jj & 15);
        hvA[tt][jj] = f2b(comb(off) * linv[jj >> 4][tt]);
    }
    #pragma unroll
    for (int r = 0; r < 2; r++) {
        int i = tid + r * 256;
        int hh = i >> 6, c = (i >> 4) & 3, tt = i & 15;
        size_t off = ((size_t)(b * 8 + hh) * 2048 + t0 + tt) * 24 + 16 + c;
        float v = comb(off) * linv[hh][tt];
        if (c == 0) gamma[hh][tt] = v; else wx[hh][c - 1][tt] = v;
    }
    __syncthreads();

    const f32x4 zero = {0.f, 0.f, 0.f, 0.f};
    #pragma unroll
    for (int nt = 0; nt < 4; nt++) {
        int col = nq * 64 + nt * 16 + m_;
        f32x4 acc = zero;
        #pragma unroll
        for (int kc = 0; kc < 4; kc++) {
            s16x8 af = *(const s16x8*)&hvA[m_][kc * 32 + quad * 8];
            const s16x8 bf = *(const s16x8*)(howT
                + (size_t)col * 128 + kc * 32 + quad * 8);
            acc = __builtin_amdgcn_mfma_f32_16x16x32_bf16(af, bf, acc, 0, 0, 0);
        }
        float bia = hob[col];
        size_t base = ((size_t)b * 256 + col) * 2048 + t0 + quad * 4;
        float4 hold = *(const float4*)(hin + base);
        float4 hres;
        hres.x = hold.x + acc[0] + bia;
        hres.y = hold.y + acc[1] + bia;
        hres.z = hold.z + acc[2] + bia;
        hres.w = hold.w + acc[3] + bia;
        *(float4*)(out + 24576 + base) = hres;
    }

    if (tid < 16) {
        int tt = tid;
        int t = t0 + tt;
        float Vu[3], xv[3];
        #pragma unroll
        for (int c = 0; c < 3; c++) {
            xv[c] = x[((size_t)b * 3 + c) * 2048 + t];
            float s = 0.f;
            #pragma unroll
            for (int v = 0; v < 8; v++)
                s += (gamma[v][tt] * xv[c] - wx[v][c][tt]) * weff[v];
            Vu[c] = s;
        }
        float gate = sqrtf(Vu[0]*Vu[0] + Vu[1]*Vu[1] + Vu[2]*Vu[2]);
        float sg = 1.f / (1.f + __expf(-gate));
        #pragma unroll
        for (int c = 0; c < 3; c++)
            out[((size_t)b * 3 + c) * 2048 + t] = xv[c] + sg * Vu[c];
    }
}

// ---------------------------------------------------------------------------
extern "C" void kernel_launch(void* const* d_in, const int* in_sizes, int n_in,
                              void* d_out, int out_size, void* d_ws,
                              size_t ws_size, hipStream_t stream)
{
    const float* x    = (const float*)d_in[0];
    const float* h    = (const float*)d_in[1];
    const float* qw1  = (const float*)d_in[2];
    const float* qb1  = (const float*)d_in[3];
    const float* qw2  = (const float*)d_in[4];
    const float* qb2  = (const float*)d_in[5];
    const float* kw1  = (const float*)d_in[6];
    const float* kb1  = (const float*)d_in[7];
    const float* kw2  = (const float*)d_in[8];
    const float* kb2  = (const float*)d_in[9];
    const float* vw1  = (const float*)d_in[10];
    const float* vb1  = (const float*)d_in[11];
    const float* vw2  = (const float*)d_in[12];
    const float* vb2  = (const float*)d_in[13];
    const float* xmw1 = (const float*)d_in[14];
    const float* xmb1 = (const float*)d_in[15];
    const float* xmw2 = (const float*)d_in[16];
    const float* xmb2 = (const float*)d_in[17];
    const float* how  = (const float*)d_in[18];
    const float* hob  = (const float*)d_in[19];
    const float* Wh   = (const float*)d_in[20];
    const float* Wu   = (const float*)d_in[21];
    float* out = (float*)d_out;

    unsigned short* q_bf  = (unsigned short*)d_ws;          // 32*2048*16 us
    unsigned short* k_bf  = q_bf + (size_t)32 * 2048 * 16;
    unsigned short* vT_bf = k_bf + (size_t)32 * 2048 * 16;  // 32*32*2048 us
    float* opart = (float*)(vT_bf + (size_t)32 * 32 * 2048); // 4*32*2048*24 f
    unsigned short* w1T  = (unsigned short*)(opart + (size_t)4 * 32 * 2048 * 24);
    unsigned short* w2T  = w1T + 98304;
    unsigned short* xm1T = w2T + 49152;
    unsigned short* xm2T = xm1T + 16384;
    unsigned short* howT = xm2T + 2048;                     // 32768 us

    wprep<<<776, 256, 0, stream>>>(qw1, kw1, vw1, qw2, kw2, vw2, xmw1, xmw2,
                                   how, w1T, w2T, xm1T, xm2T, howT);
    qkv_mfma<<<512, 256, 0, stream>>>(
        x, h, qb1, qb2, kb1, kb2, vb1, vb2, xmb1, xmb2,
        w1T, w2T, xm1T, xm2T, q_bf, k_bf, vT_bf);
    attn_mfma<<<4096, 64, 0, stream>>>(q_bf, k_bf, vT_bf, opart);
    epi_kernel<<<512, 256, 0, stream>>>(opart, howT, x, h, hob, Wh, Wu, out);
}

// Round 16
// 178.472 us; speedup vs baseline: 1.0546x; 1.0443x over previous
//
#include <hip/hip_runtime.h>
#include <hip/hip_bf16.h>
#include <math.h>

typedef __attribute__((ext_vector_type(8))) short s16x8;   // 8 bf16
typedef __attribute__((ext_vector_type(4))) float f32x4;

__device__ __forceinline__ float silu(float a) {
    return a / (1.f + __expf(-a));
}
__device__ __forceinline__ unsigned short f2b(float f) {
    __hip_bfloat16 h = __float2bfloat16(f);
    return *reinterpret_cast<unsigned short*>(&h);
}

// ---------------------------------------------------------------------------
// Kernel 0: weight prep. bf16 B-layout weights + howT for the epilogue.
// ---------------------------------------------------------------------------
__global__ __launch_bounds__(256) void wprep(
    const float* __restrict__ qw1, const float* __restrict__ kw1,
    const float* __restrict__ vw1, const float* __restrict__ qw2,
    const float* __restrict__ kw2, const float* __restrict__ vw2,
    const float* __restrict__ xmw1, const float* __restrict__ xmw2,
    const float* __restrict__ how,
    unsigned short* __restrict__ w1T, unsigned short* __restrict__ w2T,
    unsigned short* __restrict__ xm1T, unsigned short* __restrict__ xm2T,
    unsigned short* __restrict__ howT)
{
    int idx = blockIdx.x * 256 + threadIdx.x;
    if (idx < 98304) {                       // w1T: 3 * 128 * 256
        int m = idx >> 15, r = idx & 32767;
        int n = r >> 8, k = r & 255;
        const float* src = (m == 0) ? qw1 : (m == 1) ? kw1 : vw1;
        w1T[idx] = f2b(src[k * 128 + n]);
    } else if (idx < 147456) {               // w2T: 3 * 128 * 128
        int r0 = idx - 98304;
        int m = r0 >> 14, r = r0 & 16383;
        int n = r >> 7, k = r & 127;
        const float* src = (m == 0) ? qw2 : (m == 1) ? kw2 : vw2;
        w2T[r0] = f2b(src[k * 128 + n]);
    } else if (idx < 163840) {               // xm1T: 128 * 128
        int r = idx - 147456;
        int n = r >> 7, k = r & 127;
        xm1T[r] = f2b(xmw1[k * 128 + n]);
    } else if (idx < 165888) {               // xm2T: 16 * 128
        int r = idx - 163840;
        int n = r >> 7, k = r & 127;
        xm2T[r] = (n < 8) ? f2b(xmw2[k * 8 + n]) : (unsigned short)0;
    } else if (idx < 198656) {               // howT: 256 * 128
        int r = idx - 165888;
        int n = r >> 7, k = r & 127;
        howT[r] = f2b(how[k * 256 + n]);
    }
}

// ---------------------------------------------------------------------------
// Kernel 1: MFMA qkv (r13 batched structure). 16 tokens/block, 4 waves,
// grid 512. RoPE now uses __cosf/__sinf (v_cos/v_sin — the libm versions
// were ~43 us of Payne-Hanek range reduction across the dispatch).
// ---------------------------------------------------------------------------
__global__ __launch_bounds__(256) void qkv_mfma(
    const float* __restrict__ x, const float* __restrict__ h,
    const float* __restrict__ qb1, const float* __restrict__ qb2,
    const float* __restrict__ kb1, const float* __restrict__ kb2,
    const float* __restrict__ vb1, const float* __restrict__ vb2,
    const float* __restrict__ xmb1, const float* __restrict__ xmb2,
    const unsigned short* __restrict__ w1T, const unsigned short* __restrict__ w2T,
    const unsigned short* __restrict__ xm1T, const unsigned short* __restrict__ xm2T,
    unsigned short* __restrict__ q_bf, unsigned short* __restrict__ k_bf,
    unsigned short* __restrict__ vT_bf)
{
    const int blk = blockIdx.x;
    const int b   = blk >> 7;
    const int t0  = (blk & 127) << 4;
    const int tid = threadIdx.x;
    const int nq   = tid >> 6;
    const int lane = tid & 63;
    const int m_   = lane & 15;
    const int quad = lane >> 4;

    __shared__ __align__(16) unsigned short hA[16][264];
    __shared__ __align__(16) unsigned short hidQ[16][136];
    __shared__ __align__(16) unsigned short hidK[16][136];
    __shared__ __align__(16) unsigned short hidV[16][136];
    __shared__ __align__(16) unsigned short voutA[16][136];
    __shared__ float vxs[16][8];

    #pragma unroll
    for (int g = 0; g < 4; g++) {
        float4 hv = *(const float4*)(h + ((size_t)(b * 256 + tid)) * 2048
                                       + t0 + g * 4);
        hA[g * 4 + 0][tid] = f2b(hv.x);
        hA[g * 4 + 1][tid] = f2b(hv.y);
        hA[g * 4 + 2][tid] = f2b(hv.z);
        hA[g * 4 + 3][tid] = f2b(hv.w);
    }
    __syncthreads();                         // B1

    const f32x4 zero = {0.f, 0.f, 0.f, 0.f};

    {
        f32x4 aQ[2] = {zero, zero}, aK[2] = {zero, zero}, aV[2] = {zero, zero};
        #pragma unroll
        for (int kc = 0; kc < 8; kc++) {
            s16x8 af = *(const s16x8*)&hA[m_][kc * 32 + quad * 8];
            #pragma unroll
            for (int nt = 0; nt < 2; nt++) {
                size_t woff = (size_t)(nq * 32 + nt * 16 + m_) * 256
                            + kc * 32 + quad * 8;
                aQ[nt] = __builtin_amdgcn_mfma_f32_16x16x32_bf16(
                    af, *(const s16x8*)(w1T + woff), aQ[nt], 0, 0, 0);
                aK[nt] = __builtin_amdgcn_mfma_f32_16x16x32_bf16(
                    af, *(const s16x8*)(w1T + 32768 + woff), aK[nt], 0, 0, 0);
                aV[nt] = __builtin_amdgcn_mfma_f32_16x16x32_bf16(
                    af, *(const s16x8*)(w1T + 65536 + woff), aV[nt], 0, 0, 0);
            }
        }
        #pragma unroll
        for (int nt = 0; nt < 2; nt++) {
            int col = nq * 32 + nt * 16 + m_;
            float bq = qb1[col], bk = kb1[col], bv = vb1[col];
            #pragma unroll
            for (int i = 0; i < 4; i++) {
                hidQ[quad * 4 + i][col] = f2b(silu(aQ[nt][i] + bq));
                hidK[quad * 4 + i][col] = f2b(silu(aK[nt][i] + bk));
                hidV[quad * 4 + i][col] = f2b(silu(aV[nt][i] + bv));
            }
        }
    }
    __syncthreads();                         // B2

    auto gemm2 = [&](const unsigned short* w2m,
                     unsigned short (*hid)[136], f32x4 acc[2]) {
        #pragma unroll
        for (int kc = 0; kc < 4; kc++) {
            s16x8 af = *(const s16x8*)&hid[m_][kc * 32 + quad * 8];
            #pragma unroll
            for (int nt = 0; nt < 2; nt++) {
                const s16x8 bf = *(const s16x8*)(w2m
                    + (size_t)(nq * 32 + nt * 16 + m_) * 128 + kc * 32 + quad * 8);
                acc[nt] = __builtin_amdgcn_mfma_f32_16x16x32_bf16(
                    af, bf, acc[nt], 0, 0, 0);
            }
        }
    };
    auto rope_store = [&](f32x4 acc[2], const float* b2,
                          unsigned short* dst, float scale) {
        #pragma unroll
        for (int nt = 0; nt < 2; nt++) {
            int col  = nq * 32 + nt * 16 + m_;
            int head = col >> 4, dim = col & 15;
            float inv = exp2f(-(float)(dim >> 1) * 0.125f * 13.28771238f);
            float bia = b2[col];
            #pragma unroll
            for (int i = 0; i < 4; i++) {
                int t = t0 + quad * 4 + i;
                float a  = acc[nt][i] + bia;
                float pr = __shfl_xor(a, 1);
                float f  = (float)t * inv;
                float cs = __cosf(f), sn = __sinf(f);
                float o  = (dim & 1) ? (a * cs + pr * sn) : (a * cs - pr * sn);
                dst[((size_t)(b * 8 + head) * 2048 + t) * 16 + dim] =
                    f2b(o * scale);
            }
        }
    };

    {
        f32x4 aQ[2] = {zero, zero}, aK[2] = {zero, zero}, aV[2] = {zero, zero};
        gemm2(w2T,         hidQ, aQ);
        gemm2(w2T + 16384, hidK, aK);
        gemm2(w2T + 32768, hidV, aV);
        rope_store(aQ, qb2, q_bf, 0.25f);
        rope_store(aK, kb2, k_bf, 1.0f);
        #pragma unroll
        for (int nt = 0; nt < 2; nt++) {
            int col = nq * 32 + nt * 16 + m_;
            float bia = vb2[col];
            #pragma unroll
            for (int i = 0; i < 4; i++)
                voutA[quad * 4 + i][col] = f2b(aV[nt][i] + bia);
        }
    }
    __syncthreads();                         // B3

    {
        int col = tid >> 1, tg = tid & 1;
        s16x8 pk;
        #pragma unroll
        for (int e = 0; e < 8; e++)
            pk[e] = (short)voutA[tg * 8 + e][col];
        *(s16x8*)(vT_bf + ((size_t)(b * 8 + (col >> 4)) * 32 + (col & 15)) * 2048
                        + t0 + tg * 8) = pk;
    }
    {
        f32x4 acc[2] = {zero, zero};
        #pragma unroll
        for (int kc = 0; kc < 4; kc++) {
            s16x8 af = *(const s16x8*)&voutA[m_][kc * 32 + quad * 8];
            #pragma unroll
            for (int nt = 0; nt < 2; nt++) {
                const s16x8 bf = *(const s16x8*)(xm1T
                    + (size_t)(nq * 32 + nt * 16 + m_) * 128 + kc * 32 + quad * 8);
                acc[nt] = __builtin_amdgcn_mfma_f32_16x16x32_bf16(
                    af, bf, acc[nt], 0, 0, 0);
            }
        }
        #pragma unroll
        for (int nt = 0; nt < 2; nt++) {
            int col = nq * 32 + nt * 16 + m_;
            float bia = xmb1[col];
            #pragma unroll
            for (int i = 0; i < 4; i++)
                hidQ[quad * 4 + i][col] = f2b(silu(acc[nt][i] + bia));
        }
    }
    __syncthreads();                         // B4

    if (nq == 0) {
        f32x4 a2 = zero;
        #pragma unroll
        for (int kc = 0; kc < 4; kc++) {
            s16x8 af = *(const s16x8*)&hidQ[m_][kc * 32 + quad * 8];
            const s16x8 bf = *(const s16x8*)(xm2T
                + (size_t)m_ * 128 + kc * 32 + quad * 8);
            a2 = __builtin_amdgcn_mfma_f32_16x16x32_bf16(af, bf, a2, 0, 0, 0);
        }
        if (m_ < 8) {
            float bia = xmb2[m_];
            #pragma unroll
            for (int i = 0; i < 4; i++)
                vxs[quad * 4 + i][m_] = a2[i] + bia;
        }
    }
    __syncthreads();                         // B5

    #pragma unroll
    for (int r = 0; r < 2; r++) {
        int i  = tid + r * 256;
        int hh = i >> 6, c = (i >> 4) & 3, tt = i & 15;
        float val = vxs[tt][hh];
        if (c)
            val *= x[((size_t)(b * 3 + (c - 1))) * 2048 + t0 + tt];
        vT_bf[((size_t)(b * 8 + hh) * 32 + 16 + c) * 2048 + t0 + tt] = f2b(val);
    }
    if (tid < 192) {
        int hh = tid / 24, rem = tid % 24;
        int c  = 20 + (rem >> 1), tg = rem & 1;
        s16x8 z = {0,0,0,0,0,0,0,0};
        *(s16x8*)(vT_bf + ((size_t)(b * 8 + hh) * 32 + c) * 2048
                        + t0 + tg * 8) = z;
    }
}

// ---------------------------------------------------------------------------
// Kernel 2: MFMA attention (unchanged r15 winner). 4-way split, 64 q/wave,
// single-buffer Elds, grid 4096 single-wave blocks.
// ---------------------------------------------------------------------------
__global__ __launch_bounds__(64) void attn_mfma(
    const unsigned short* __restrict__ q_bf,
    const unsigned short* __restrict__ k_bf,
    const unsigned short* __restrict__ vT_bf,
    float* __restrict__ opart)
{
    const int blk  = blockIdx.x;
    const int sp   = blk >> 10;              // key split 0..3
    const int bh   = (blk >> 5) & 31;
    const int qs   = (blk & 31) << 6;        // 64-query strip
    const int lane = threadIdx.x;
    const int m_   = lane & 15;
    const int quad = lane >> 4;

    __shared__ __align__(16) unsigned short Elds[4][16 * 72];

    const s16x8 zs = {0, 0, 0, 0, 0, 0, 0, 0};
    const f32x4 zero = {0.f, 0.f, 0.f, 0.f};

    s16x8 qfrag[4];
    #pragma unroll
    for (int qt = 0; qt < 4; qt++) {
        qfrag[qt] = zs;
        if (quad < 2)
            qfrag[qt] = *(const s16x8*)(q_bf +
                ((size_t)(bh * 2048 + qs + qt * 16 + m_) * 16 + quad * 8));
    }

    f32x4 O0[4], O1[4];
    float lsq[4];
    #pragma unroll
    for (int qt = 0; qt < 4; qt++) {
        O0[qt] = zero; O1[qt] = zero; lsq[qt] = 0.f;
    }

    const unsigned short* kb = k_bf + ((size_t)bh * 2048 + sp * 512) * 16;
    const unsigned short* vb = vT_bf + (size_t)bh * 32 * 2048 + sp * 512;

    for (int kt = 0; kt < 8; kt++) {         // 8 tiles of 64 keys
        const int k0 = kt * 64;

        s16x8 kf[4];
        #pragma unroll
        for (int n = 0; n < 4; n++) {
            kf[n] = zs;
            if (quad < 2)
                kf[n] = *(const s16x8*)(kb +
                      ((size_t)(k0 + n * 16 + m_) * 16 + quad * 8));
        }
        s16x8 vf0[2], vf1[2];
        #pragma unroll
        for (int c = 0; c < 2; c++) {
            vf0[c] = *(const s16x8*)(vb + (size_t)m_ * 2048
                                        + k0 + c * 32 + quad * 8);
            vf1[c] = *(const s16x8*)(vb + (size_t)(16 + m_) * 2048
                                        + k0 + c * 32 + quad * 8);
        }

        #pragma unroll
        for (int qt = 0; qt < 4; qt++) {
            #pragma unroll
            for (int n = 0; n < 4; n++) {
                f32x4 E = __builtin_amdgcn_mfma_f32_16x16x32_bf16(
                    kf[n], qfrag[qt], zero, 0, 0, 0);
                float e0 = __expf(E[0]);
                float e1 = __expf(E[1]);
                float e2 = __expf(E[2]);
                float e3 = __expf(E[3]);
                lsq[qt] += e0 + e1 + e2 + e3;
                uint2 pk;
                pk.x = (unsigned)f2b(e0) | ((unsigned)f2b(e1) << 16);
                pk.y = (unsigned)f2b(e2) | ((unsigned)f2b(e3) << 16);
                *(uint2*)&Elds[qt][m_ * 72 + n * 16 + quad * 4] = pk;
            }
        }
        __builtin_amdgcn_s_waitcnt(0xc07f);  // lgkmcnt(0), wave-local RAW

        #pragma unroll
        for (int qt = 0; qt < 4; qt++) {
            #pragma unroll
            for (int c = 0; c < 2; c++) {
                s16x8 af = *(const s16x8*)
                    &Elds[qt][m_ * 72 + c * 32 + quad * 8];
                O0[qt] = __builtin_amdgcn_mfma_f32_16x16x32_bf16(
                    af, vf0[c], O0[qt], 0, 0, 0);
                O1[qt] = __builtin_amdgcn_mfma_f32_16x16x32_bf16(
                    af, vf1[c], O1[qt], 0, 0, 0);
            }
        }
    }

    #pragma unroll
    for (int qt = 0; qt < 4; qt++) {
        float s = lsq[qt];
        s += __shfl_xor(s, 16);
        s += __shfl_xor(s, 32);
        float* opb = opart + ((size_t)(sp * 32 + bh) * 2048 + qs + qt * 16) * 24;
        #pragma unroll
        for (int i = 0; i < 4; i++) {
            int row = quad * 4 + i;
            float* ob = opb + row * 24;
            ob[m_] = O0[qt][i];
            if (m_ < 4) ob[16 + m_] = O1[qt][i];
        }
        if (quad == 0) opb[m_ * 24 + 20] = s;
    }
}

// ---------------------------------------------------------------------------
// Kernel 3: MFMA epilogue, 4-split combine, COALESCED opart reads
// (consecutive lanes read consecutive feature cols). 16 tokens/block, grid 512.
// ---------------------------------------------------------------------------
__global__ __launch_bounds__(256) void epi_kernel(
    const float* __restrict__ opart, const unsigned short* __restrict__ howT,
    const float* __restrict__ x, const float* __restrict__ hin,
    const float* __restrict__ hob,
    const float* __restrict__ Wh, const float* __restrict__ Wu,
    float* __restrict__ out)
{
    const int blk = blockIdx.x;
    const int b  = blk >> 7;
    const int t0 = (blk & 127) << 4;
    const int tid = threadIdx.x;
    const int nq   = tid >> 6;
    const int lane = tid & 63;
    const int m_   = lane & 15;
    const int quad = lane >> 4;
    const size_t qtr = (size_t)32 * 2048 * 24;

    __shared__ __align__(16) unsigned short hvA[16][136];
    __shared__ float linv[8][16];
    __shared__ float gamma[8][16], wx[8][3][16];
    __shared__ float weff[8];

    auto comb = [&](size_t off) -> float {
        return opart[off] + opart[qtr + off] + opart[2 * qtr + off]
             + opart[3 * qtr + off];
    };

    if (tid < 128) {
        int hh = tid >> 4, tt = tid & 15;
        size_t off = ((size_t)(b * 8 + hh) * 2048 + t0 + tt) * 24 + 20;
        linv[hh][tt] = 1.f / comb(off);
    } else if (tid < 136) {
        int v = tid - 128;
        float s = 0.f;
        for (int j = 0; j < 8; j++) s += Wh[v * 8 + j] * Wu[j];
        weff[v] = s;
    }
    __syncthreads();

    // coalesced: consecutive lanes -> consecutive feature col within a head
    #pragma unroll
    for (int r = 0; r < 8; r++) {
        int i = tid + r * 256;               // 0..2047
        int tt = i >> 7, jj = i & 127;       // token, feature
        size_t off = ((size_t)(b * 8 + (jj >> 4)) * 2048 + t0 + tt) * 24
                   + (jj & 15);
        hvA[tt][jj] = f2b(comb(off) * linv[jj >> 4][tt]);
    }
    #pragma unroll
    for (int r = 0; r < 2; r++) {
        int i = tid + r * 256;               // 0..511
        int tt = i >> 5, sub = i & 31;
        int hh = sub >> 2, c = sub & 3;
        size_t off = ((size_t)(b * 8 + hh) * 2048 + t0 + tt) * 24 + 16 + c;
        float v = comb(off) * linv[hh][tt];
        if (c == 0) gamma[hh][tt] = v; else wx[hh][c - 1][tt] = v;
    }
    __syncthreads();

    const f32x4 zero = {0.f, 0.f, 0.f, 0.f};
    #pragma unroll
    for (int nt = 0; nt < 4; nt++) {
        int col = nq * 64 + nt * 16 + m_;
        f32x4 acc = zero;
        #pragma unroll
        for (int kc = 0; kc < 4; kc++) {
            s16x8 af = *(const s16x8*)&hvA[m_][kc * 32 + quad * 8];
            const s16x8 bf = *(const s16x8*)(howT
                + (size_t)col * 128 + kc * 32 + quad * 8);
            acc = __builtin_amdgcn_mfma_f32_16x16x32_bf16(af, bf, acc, 0, 0, 0);
        }
        float bia = hob[col];
        size_t base = ((size_t)b * 256 + col) * 2048 + t0 + quad * 4;
        float4 hold = *(const float4*)(hin + base);
        float4 hres;
        hres.x = hold.x + acc[0] + bia;
        hres.y = hold.y + acc[1] + bia;
        hres.z = hold.z + acc[2] + bia;
        hres.w = hold.w + acc[3] + bia;
        *(float4*)(out + 24576 + base) = hres;
    }

    if (tid < 16) {
        int tt = tid;
        int t = t0 + tt;
        float Vu[3], xv[3];
        #pragma unroll
        for (int c = 0; c < 3; c++) {
            xv[c] = x[((size_t)b * 3 + c) * 2048 + t];
            float s = 0.f;
            #pragma unroll
            for (int v = 0; v < 8; v++)
                s += (gamma[v][tt] * xv[c] - wx[v][c][tt]) * weff[v];
            Vu[c] = s;
        }
        float gate = sqrtf(Vu[0]*Vu[0] + Vu[1]*Vu[1] + Vu[2]*Vu[2]);
        float sg = 1.f / (1.f + __expf(-gate));
        #pragma unroll
        for (int c = 0; c < 3; c++)
            out[((size_t)b * 3 + c) * 2048 + t] = xv[c] + sg * Vu[c];
    }
}

// ---------------------------------------------------------------------------
extern "C" void kernel_launch(void* const* d_in, const int* in_sizes, int n_in,
                              void* d_out, int out_size, void* d_ws,
                              size_t ws_size, hipStream_t stream)
{
    const float* x    = (const float*)d_in[0];
    const float* h    = (const float*)d_in[1];
    const float* qw1  = (const float*)d_in[2];
    const float* qb1  = (const float*)d_in[3];
    const float* qw2  = (const float*)d_in[4];
    const float* qb2  = (const float*)d_in[5];
    const float* kw1  = (const float*)d_in[6];
    const float* kb1  = (const float*)d_in[7];
    const float* kw2  = (const float*)d_in[8];
    const float* kb2  = (const float*)d_in[9];
    const float* vw1  = (const float*)d_in[10];
    const float* vb1  = (const float*)d_in[11];
    const float* vw2  = (const float*)d_in[12];
    const float* vb2  = (const float*)d_in[13];
    const float* xmw1 = (const float*)d_in[14];
    const float* xmb1 = (const float*)d_in[15];
    const float* xmw2 = (const float*)d_in[16];
    const float* xmb2 = (const float*)d_in[17];
    const float* how  = (const float*)d_in[18];
    const float* hob  = (const float*)d_in[19];
    const float* Wh   = (const float*)d_in[20];
    const float* Wu   = (const float*)d_in[21];
    float* out = (float*)d_out;

    unsigned short* q_bf  = (unsigned short*)d_ws;          // 32*2048*16 us
    unsigned short* k_bf  = q_bf + (size_t)32 * 2048 * 16;
    unsigned short* vT_bf = k_bf + (size_t)32 * 2048 * 16;  // 32*32*2048 us
    float* opart = (float*)(vT_bf + (size_t)32 * 32 * 2048); // 4*32*2048*24 f
    unsigned short* w1T  = (unsigned short*)(opart + (size_t)4 * 32 * 2048 * 24);
    unsigned short* w2T  = w1T + 98304;
    unsigned short* xm1T = w2T + 49152;
    unsigned short* xm2T = xm1T + 16384;
    unsigned short* howT = xm2T + 2048;                     // 32768 us

    wprep<<<776, 256, 0, stream>>>(qw1, kw1, vw1, qw2, kw2, vw2, xmw1, xmw2,
                                   how, w1T, w2T, xm1T, xm2T, howT);
    qkv_mfma<<<512, 256, 0, stream>>>(
        x, h, qb1, qb2, kb1, kb2, vb1, vb2, xmb1, xmb2,
        w1T, w2T, xm1T, xm2T, q_bf, k_bf, vT_bf);
    attn_mfma<<<4096, 64, 0, stream>>>(q_bf, k_bf, vT_bf, opart);
    epi_kernel<<<512, 256, 0, stream>>>(opart, howT, x, h, hob, Wh, Wu, out);
}